// Round 6
// baseline (212.541 us; speedup 1.0000x reference)
//
#include <hip/hip_runtime.h>
#include <math.h>

// Problem constants: C=256, H=W=128, PH=PW=8.
#define C_ 256
#define H_ 128
#define W_ 128
#define PH_ 8
#define PW_ 8
#define HW_ (H_ * W_)
#define LDS_S 130   // colmax row stride (floats): even (b64-aligned), non-pow2

// One fused kernel. Block = (n, ph, cg). cg = bid&7 -> XCD-affine 32-channel
// group (per-XCD fm footprint 2 MB, L2-resident). 256 threads = 4 waves.
//
// Phase 1 (h-pool): wave w handles channels cl = 8w..8w+7. For each channel,
// lane covers absolute columns {2*lane, 2*lane+1}; predicated float2 loads
// over the bin's rows accumulate a per-column max, stored to LDS colmax.
// Loads across the 8 channels are independent -> deep memory-level parallelism.
//
// Phase 2 (w-pool): thread = (cl = tid>>3, pw = tid&7) reduces its w-bin
// [ws, we) from LDS with 17 independent clamped reads (max is idempotent),
// then stores; consecutive 8 threads write 32 B-contiguous output.
__global__ __launch_bounds__(256) void roi_pool_fused(
    const float* __restrict__ fm,
    const int* __restrict__ rois,
    float* __restrict__ out,
    int N)
{
    __shared__ float colmax[32 * LDS_S];

    const int bid = blockIdx.x;
    const int cg  = bid & 7;            // XCD-affine channel group
    const int t   = bid >> 3;
    const int ph  = t & 7;
    const int n   = t >> 3;

    const int tid  = threadIdx.x;
    const int wid  = tid >> 6;
    const int lane = tid & 63;

    const int4 roi = ((const int4*)rois)[n];
    const int y = roi.x, x = roi.y, rH = roi.z, rW = roi.w;

    // h-bin = [floor(ph*rH/8), ceil((ph+1)*rH/8))  (verified union of idA/idB)
    const int hs = (ph * rH) >> 3;
    const int he = ((ph + 1) * rH + 7) >> 3;
    const int nrows = he - hs;          // wave-uniform, 1..17

    const int col0   = lane << 1;
    const bool active = (col0 + 1 >= x) && (col0 < x + rW);

    const size_t rp = W_ / 2;           // row pitch in float2

    // ---------- Phase 1 ----------
    #pragma unroll 2
    for (int k = 0; k < 8; ++k) {
        const int cl = (wid << 3) + k;  // 0..31, wave-uniform
        const int c  = (cg << 5) + cl;
        float m0 = -INFINITY, m1 = -INFINITY;
        if (active) {
            const float2* p = (const float2*)(fm + (size_t)c * HW_)
                              + (size_t)(y + hs) * rp + lane;
            int cnt = nrows;
            while (cnt >= 4) {
                const float2 a = p[0];
                const float2 b = p[rp];
                const float2 d = p[2 * rp];
                const float2 e = p[3 * rp];
                p += 4 * rp; cnt -= 4;
                m0 = fmaxf(m0, fmaxf(fmaxf(a.x, b.x), fmaxf(d.x, e.x)));
                m1 = fmaxf(m1, fmaxf(fmaxf(a.y, b.y), fmaxf(d.y, e.y)));
            }
            while (cnt > 0) {
                const float2 a = p[0];
                p += rp; --cnt;
                m0 = fmaxf(m0, a.x);
                m1 = fmaxf(m1, a.y);
            }
        }
        // cols outside [x, x+rW) hold stale/-inf values; never read in phase 2.
        *(float2*)(colmax + cl * LDS_S + col0) = make_float2(m0, m1);
    }
    __syncthreads();

    // ---------- Phase 2 ----------
    const int pw  = tid & 7;
    const int cl2 = tid >> 3;           // 0..31
    const int ws  = (pw * rW) >> 3;                 // floor(pw*rW/8)
    const int we  = (((pw + 1) * rW) + 7) >> 3;     // ceil((pw+1)*rW/8)
    const int bm  = we - ws - 1;        // 0..16

    const float* base = colmax + cl2 * LDS_S + x + ws;
    // 17 independent clamped reads (re-reading the last in-bin column is
    // harmless for max); single lgkmcnt wait, then a flat fmax tree.
    float v0  = base[0];
    float v1  = base[min(1,  bm)];
    float v2  = base[min(2,  bm)];
    float v3  = base[min(3,  bm)];
    float v4  = base[min(4,  bm)];
    float v5  = base[min(5,  bm)];
    float v6  = base[min(6,  bm)];
    float v7  = base[min(7,  bm)];
    float v8  = base[min(8,  bm)];
    float v9  = base[min(9,  bm)];
    float v10 = base[min(10, bm)];
    float v11 = base[min(11, bm)];
    float v12 = base[min(12, bm)];
    float v13 = base[min(13, bm)];
    float v14 = base[min(14, bm)];
    float v15 = base[min(15, bm)];
    float v16 = base[min(16, bm)];

    float r = fmaxf(
        fmaxf(fmaxf(fmaxf(v0, v1), fmaxf(v2, v3)),
              fmaxf(fmaxf(v4, v5), fmaxf(v6, v7))),
        fmaxf(fmaxf(fmaxf(v8, v9), fmaxf(v10, v11)),
              fmaxf(fmaxf(v12, v13), fmaxf(v14, fmaxf(v15, v16)))));

    const int c = (cg << 5) + cl2;
    out[(size_t)n * (C_ * PH_ * PW_) + c * (PH_ * PW_) + ph * PW_ + pw] = r;
}

extern "C" void kernel_launch(void* const* d_in, const int* in_sizes, int n_in,
                              void* d_out, int out_size, void* d_ws, size_t ws_size,
                              hipStream_t stream) {
    const float* fm   = (const float*)d_in[0];
    const int*   rois = (const int*)d_in[1];
    float*       out  = (float*)d_out;
    const int N = in_sizes[1] / 4;

    dim3 grid(N * PH_ * 8);   // (n, ph, cg): cg = bid&7 -> XCD
    roi_pool_fused<<<grid, 256, 0, stream>>>(fm, rois, out, N);
}

// Round 7
// 146.439 us; speedup vs baseline: 1.4514x; 1.4514x over previous
//
#include <hip/hip_runtime.h>
#include <math.h>

// Problem constants: C=256, H=W=128, PH=PW=8.
#define C_ 256
#define H_ 128
#define W_ 128
#define PH_ 8
#define PW_ 8
#define HW_ (H_ * W_)

__device__ __forceinline__ float4 max4(float4 a, float4 b) {
    return make_float4(fmaxf(a.x, b.x), fmaxf(a.y, b.y),
                       fmaxf(a.z, b.z), fmaxf(a.w, b.w));
}

// ---------- Kernel 1: transpose (C, H*W) -> (H*W, C), XCD-affine ----------
// (unchanged from R4: ~10 us, conflict-free, writes land in the consuming
// XCD's L2 because bid&7 = channel group = the pool's bid&7.)
__global__ __launch_bounds__(256) void transpose_kernel(
    const float* __restrict__ fm, float* __restrict__ fmt)
{
    __shared__ float tile[32 * 257];
    const int tid = threadIdx.x;
    const int g   = blockIdx.x & 7;
    const int hwb = blockIdx.x >> 3;
    const int c0  = g * 32;
    const int hw0 = hwb * 256;

    const int l    = tid & 63;
    const int crow = tid >> 6;
    const int sw   = (l >> 3) & 3;
    #pragma unroll
    for (int k = 0; k < 8; ++k) {
        const int c = crow + 4 * k;
        const float4 v = *(const float4*)(fm + (size_t)(c0 + c) * HW_ + hw0 + 4 * l);
        float* t = tile + c * 257 + 4 * l;
        t[(0 + sw) & 3] = v.x;
        t[(1 + sw) & 3] = v.y;
        t[(2 + sw) & 3] = v.z;
        t[(3 + sw) & 3] = v.w;
    }
    __syncthreads();

    const int cq  = tid & 7;
    const int hwr = tid >> 3;
    #pragma unroll
    for (int m = 0; m < 8; ++m) {
        const int hw = hwr + 32 * m;
        const int o  = (hw & ~3) | (((hw & 3) + m) & 3);
        float4 w;
        w.x = tile[(4 * cq + 0) * 257 + o];
        w.y = tile[(4 * cq + 1) * 257 + o];
        w.z = tile[(4 * cq + 2) * 257 + o];
        w.w = tile[(4 * cq + 3) * 257 + o];
        *(float4*)(fmt + (size_t)(hw0 + hw) * C_ + c0 + 4 * cq) = w;
    }
}

// ---------- Kernel 2: pooling, channel-major, exact footprint ----------
// R2's winning structure (w-steps outer-specialized, h inner, dwordx4 loads)
// with the tail w-step exec-masked (pg < rem) instead of clamped: masked
// lanes issue no L2 requests -> read bytes ~1.5 GB instead of 2.55 GB.
__global__ __launch_bounds__(256) void pool_kernel(
    const float* __restrict__ fmt, const int* __restrict__ rois,
    float* __restrict__ out, int N)
{
    const int bid = blockIdx.x;
    const int cg  = bid & 7;                 // XCD-affine channel group
    const int m   = bid >> 3;
    const int pq  = m & 1;
    const int ph  = (m >> 1) & 7;
    const int n   = m >> 4;

    const int wid  = threadIdx.x >> 6;
    const int lane = threadIdx.x & 63;
    const int pw   = pq * 4 + wid;           // wave-uniform
    const int pg   = lane >> 3;              // position group 0..7
    const int c    = (cg << 5) + ((lane & 7) << 2);

    const int4 roi = ((const int4*)rois)[n];
    const int y = roi.x, x = roi.y, rH = roi.z, rW = roi.w;

    const int hs = (ph * rH) >> 3;
    const int he = ((ph + 1) * rH + 7) >> 3;
    const int nrows = he - hs;               // wave-uniform, 1..17
    const int ws = (pw * rW) >> 3;
    const int we = ((pw + 1) * rW + 7) >> 3;
    const int bw = we - ws;                  // 1..17
    const int nfull = (bw - 1) >> 3;         // 0,1,2 (wave-uniform)
    const int rem   = bw - 8 * nfull;        // 1..8 lanes active in tail step

    const float* rowbase = fmt + ((size_t)(y + hs) * W_ + x) * C_ + c;
    const size_t HSF = (size_t)W_ * C_;      // h stride in floats

    float4 acc = make_float4(-INFINITY, -INFINITY, -INFINITY, -INFINITY);

    // ---- tail step (always present; only lanes pg < rem participate) ----
    if (pg < rem) {
        const float* p = rowbase + (size_t)(ws + 8 * nfull + pg) * C_;
        int cnt = nrows;
        while (cnt >= 4) {
            const float4 a = *(const float4*)(p);
            const float4 b = *(const float4*)(p + HSF);
            const float4 d = *(const float4*)(p + 2 * HSF);
            const float4 e = *(const float4*)(p + 3 * HSF);
            p += 4 * HSF; cnt -= 4;
            acc = max4(acc, max4(max4(a, b), max4(d, e)));
        }
        while (cnt > 0) {
            const float4 a = *(const float4*)(p);
            p += HSF; --cnt;
            acc = max4(acc, a);
        }
    }

    // ---- full steps (all 8 lanes) ----
    if (nfull > 0) {
        const float* p = rowbase + (size_t)(ws + pg) * C_;
        int cnt = nrows;
        while (cnt >= 4) {
            const float4 a = *(const float4*)(p);
            const float4 b = *(const float4*)(p + HSF);
            const float4 d = *(const float4*)(p + 2 * HSF);
            const float4 e = *(const float4*)(p + 3 * HSF);
            p += 4 * HSF; cnt -= 4;
            acc = max4(acc, max4(max4(a, b), max4(d, e)));
        }
        while (cnt > 0) {
            const float4 a = *(const float4*)(p);
            p += HSF; --cnt;
            acc = max4(acc, a);
        }
    }
    if (nfull > 1) {
        const float* p = rowbase + (size_t)(ws + 8 + pg) * C_;
        int cnt = nrows;
        while (cnt >= 4) {
            const float4 a = *(const float4*)(p);
            const float4 b = *(const float4*)(p + HSF);
            const float4 d = *(const float4*)(p + 2 * HSF);
            const float4 e = *(const float4*)(p + 3 * HSF);
            p += 4 * HSF; cnt -= 4;
            acc = max4(acc, max4(max4(a, b), max4(d, e)));
        }
        while (cnt > 0) {
            const float4 a = *(const float4*)(p);
            p += HSF; --cnt;
            acc = max4(acc, a);
        }
    }

    // reduce across the 8 position groups (fixed xor swizzles, conflict-free)
    #pragma unroll
    for (int mask = 8; mask <= 32; mask <<= 1) {
        acc.x = fmaxf(acc.x, __shfl_xor(acc.x, mask, 64));
        acc.y = fmaxf(acc.y, __shfl_xor(acc.y, mask, 64));
        acc.z = fmaxf(acc.z, __shfl_xor(acc.z, mask, 64));
        acc.w = fmaxf(acc.w, __shfl_xor(acc.w, mask, 64));
    }

    if (lane < 8) {
        float* o = out + ((size_t)n * C_ + c) * (PH_ * PW_) + ph * PW_ + pw;
        o[0]               = acc.x;
        o[PH_ * PW_]       = acc.y;
        o[2 * (PH_ * PW_)] = acc.z;
        o[3 * (PH_ * PW_)] = acc.w;
    }
}

// ---------- Fallback (R1 kernel) if ws is too small for the transpose ----------
__global__ __launch_bounds__(256) void roi_pool_fallback(
    const float* __restrict__ fm, const int* __restrict__ rois,
    float* __restrict__ out, int N)
{
    const int wid  = threadIdx.x >> 6;
    const int lane = threadIdx.x & 63;
    const int bid  = blockIdx.x;
    const int xcd  = bid & 7;
    const int t    = bid >> 3;
    const int csub = t & 7;
    const int n    = t >> 3;
    if (n >= N) return;
    const int c = (xcd << 5) + (csub << 2) + wid;

    const int4 roi = ((const int4*)rois)[n];
    const int y = roi.x, x = roi.y, rH = roi.z, rW = roi.w;

    const float2* plane2 = (const float2*)(fm + (size_t)c * (H_ * W_));
    const int pw = lane & 7;
    const int j  = lane >> 3;
    const int ws = (pw * rW) >> 3;
    const int we = (((pw + 1) * rW) + 7) >> 3;

    #pragma unroll
    for (int ph = 0; ph < PH_; ++ph) {
        const int hs = (ph * rH) >> 3;
        const int he = ((ph + 1) * rH + 7) >> 3;
        const float2* p = plane2 + (size_t)(y + hs) * (W_ / 2) + lane;
        float m0 = -INFINITY, m1 = -INFINITY;
        int cnt = he - hs;
        while (cnt >= 2) {
            const float2 a = p[0];
            const float2 b = p[W_ / 2];
            p += W_; cnt -= 2;
            m0 = fmaxf(m0, fmaxf(a.x, b.x));
            m1 = fmaxf(m1, fmaxf(a.y, b.y));
        }
        if (cnt) { const float2 a = p[0]; m0 = fmaxf(m0, a.x); m1 = fmaxf(m1, a.y); }

        float r = -INFINITY;
        #pragma unroll
        for (int k = 0; k < 3; ++k) {
            const int w  = ws + j + k * 8;
            const int wa = x + w;
            const float a = __shfl(m0, (wa >> 1) & 63, 64);
            const float b = __shfl(m1, (wa >> 1) & 63, 64);
            if (w < we) r = fmaxf(r, (wa & 1) ? b : a);
        }
        r = fmaxf(r, __shfl_xor(r, 8, 64));
        r = fmaxf(r, __shfl_xor(r, 16, 64));
        r = fmaxf(r, __shfl_xor(r, 32, 64));
        if (lane < PW_) out[(((size_t)n * C_ + c) * PH_ + ph) * PW_ + lane] = r;
    }
}

extern "C" void kernel_launch(void* const* d_in, const int* in_sizes, int n_in,
                              void* d_out, int out_size, void* d_ws, size_t ws_size,
                              hipStream_t stream) {
    const float* fm   = (const float*)d_in[0];
    const int*   rois = (const int*)d_in[1];
    float*       out  = (float*)d_out;
    const int N = in_sizes[1] / 4;

    const size_t need = (size_t)HW_ * C_ * sizeof(float);
    if (ws_size >= need) {
        float* fmt = (float*)d_ws;
        transpose_kernel<<<dim3((HW_ / 256) * 8), 256, 0, stream>>>(fm, fmt);
        pool_kernel<<<dim3(N * 128), 256, 0, stream>>>(fmt, rois, out, N);
    } else {
        roi_pool_fallback<<<dim3(64 * N), 256, 0, stream>>>(fm, rois, out, N);
    }
}